// Round 10
// baseline (65.302 us; speedup 1.0000x reference)
//
#include <hip/hip_runtime.h>
#include <hip/hip_bf16.h>

// DLRM-like, round 10: SPB=16 megakernel with double-buffered weight staging
// and single-sync K-steps (2-phase template): STAGE(buf^1); compute(buf); sync.
//
// ws layout (bytes):
//   [0,      32768)   W0t 512x32  bf16 (k>=13 zero)
//   [32768,  294912)  W1t 256x512 bf16
//   [294912, 327680)  W2t 64x256  bf16
//   [327680, 540672)  Wtt 256x416 bf16 (k>=389 zero)

#define BATCH   16384
#define NSPARSE 26
#define VOCAB   100000
#define EMB     64
#define KTOP    416
#define KREAL   389
#define SPB     16
#define ASTR    424   // shorts; row stride 212 dw -> <=2-way on frag reads
#define X1STR   520   // 260 dw
#define X2STR   264   // 132 dw

typedef __attribute__((ext_vector_type(8)))  short bf16x8;
typedef __attribute__((ext_vector_type(4)))  short s16x4;
typedef __attribute__((ext_vector_type(4)))  float f32x4;
typedef __attribute__((ext_vector_type(16))) float f32x16;

__device__ inline void gload_lds16(const void* g, void* l) {
    __builtin_amdgcn_global_load_lds(
        (const __attribute__((address_space(1))) void*)g,
        (__attribute__((address_space(3))) void*)l, 16, 0, 0);
}

__device__ inline short f2bf(float x) {
    __hip_bfloat16 h = __float2bfloat16(x);
    return *reinterpret_cast<short*>(&h);
}

// ------------------------------------------------- prep: tiled transpose ----
__global__ __launch_bounds__(256)
void prep_weights(const float* __restrict__ W0, const float* __restrict__ W1,
                  const float* __restrict__ W2, const float* __restrict__ Wt,
                  short* __restrict__ W0t, short* __restrict__ W1t,
                  short* __restrict__ W2t, short* __restrict__ Wtt)
{
    __shared__ float tile[32][36];
    int b = blockIdx.x, t = threadIdx.x;
    const float* src; short* dst; int K, N, Kpad, k0, n0;
    if (b < 16)        {              src = W0; dst = W0t; K = 13;  N = 512; Kpad = 32;  k0 = 0;           n0 = b * 32; }
    else if (b < 144)  { int i = b - 16;  src = W1; dst = W1t; K = 512; N = 256; Kpad = 512; k0 = (i >> 3) * 32; n0 = (i & 7) * 32; }
    else if (b < 160)  { int i = b - 144; src = W2; dst = W2t; K = 256; N = 64;  Kpad = 256; k0 = (i >> 1) * 32; n0 = (i & 1) * 32; }
    else               { int i = b - 160; src = Wt; dst = Wtt; K = 389; N = 256; Kpad = 416; k0 = (i >> 3) * 32; n0 = (i & 7) * 32; }

    int r = t >> 3, c4 = (t & 7) * 4;
    int gr = k0 + r;
    float4 v = make_float4(0.f, 0.f, 0.f, 0.f);
    if (gr < K) v = *(const float4*)(src + (size_t)gr * N + n0 + c4);
    tile[r][c4 + 0] = v.x; tile[r][c4 + 1] = v.y;
    tile[r][c4 + 2] = v.z; tile[r][c4 + 3] = v.w;
    __syncthreads();
    s16x4 o;
    #pragma unroll
    for (int j = 0; j < 4; ++j) o[j] = f2bf(tile[c4 + j][r]);
    *(s16x4*)&dst[(size_t)(n0 + r) * Kpad + k0 + c4] = o;
}

// ------------------------------------------------------------ megakernel ----
__global__ __launch_bounds__(256, 2)
void fused_all(const int* __restrict__ sparse, const float* __restrict__ tables,
               const float* __restrict__ D,
               const short* __restrict__ W0t, const float* __restrict__ b0,
               const short* __restrict__ W1t, const float* __restrict__ b1,
               const short* __restrict__ W2t, const float* __restrict__ b2,
               const short* __restrict__ Wtt, const float* __restrict__ bt,
               float* __restrict__ out)
{
    // Ds 1K | As 13.6K | X1s 16.6K | X2s 8.4K | Bst0 16K | Bst1 16K = 72448 B
    __shared__ __align__(16) char smem[72448];
    short* Ds   = (short*)(smem);
    short* As   = (short*)(smem + 1024);
    short* X1s  = (short*)(smem + 14592);
    short* X2s  = (short*)(smem + 31232);
    short* Bst0 = (short*)(smem + 39680);
    short* Bst1 = (short*)(smem + 56064);
    short* Bst[2] = {Bst0, Bst1};

    int tid = threadIdx.x;
    int w = tid >> 6, lane = tid & 63;
    int lr = lane & 15, lg = lane >> 4;
    int swz = (lg ^ (lr & 3)) * 8;        // matches source kc^(n&3) pre-swizzle
    int sbase = blockIdx.x * SPB;

    // staging helpers (single-sync 2-phase schedule)
    auto stage256 = [&](short* dstBuf, const short* W, int ldw, int k0) {
        #pragma unroll
        for (int rd = 0; rd < 4; ++rd) {
            int slot = rd * 256 + tid;
            int n = slot >> 2, kc = slot & 3;
            gload_lds16(W + (size_t)n * ldw + k0 + (kc ^ (n & 3)) * 8,
                        dstBuf + slot * 8);
        }
    };
    auto stage64 = [&](short* dstBuf, const short* W, int ldw, int k0) {
        int n = tid >> 2, kc = tid & 3;
        gload_lds16(W + (size_t)n * ldw + k0 + (kc ^ (n & 3)) * 8,
                    dstBuf + tid * 8);
    };

    // stage Ds (16x13 f32 -> bf16, pad to K=32) + zero As pad cols 389..415
    for (int x = tid; x < SPB * 13; x += 256) {
        int r = x / 13, k = x - r * 13;
        Ds[r * 32 + k] = f2bf(D[(size_t)sbase * 13 + x]);
    }
    for (int x = tid; x < SPB * 19; x += 256) {
        int r = x / 19, k = 13 + (x - r * 19);
        Ds[r * 32 + k] = 0;
    }
    for (int x = tid; x < SPB * 27; x += 256) {
        int r = x / 27, c = x - r * 27;
        As[r * ASTR + KREAL + c] = 0;
    }
    __syncthreads();

    // ---- gram phase: wave w -> samples w*4..w*4+3, 2-deep load pipeline ----
    auto gram_phase = [&]() {
        int row = lane & 31, half = lane >> 5;
        int srow = (row < NSPARSE) ? row : 0;   // lanes>=26 duplicate row 0;
        int idxv[4];                            // garbage lands in r,c>=26 only
        #pragma unroll
        for (int li = 0; li < 4; ++li)
            idxv[li] = sparse[(sbase + w * 4 + li) * NSPARSE + srow];

        f32x4 Ca[4], Cb[4], Na[4], Nb[4];
        {
            const float* rp = tables + ((long)srow * VOCAB + idxv[0]) * EMB + half * 8;
            #pragma unroll
            for (int t = 0; t < 4; ++t) {
                Ca[t] = *(const f32x4*)(rp + t * 16);
                Cb[t] = *(const f32x4*)(rp + t * 16 + 4);
            }
        }
        #pragma unroll
        for (int li = 0; li < 4; ++li) {
            if (li < 3) {
                const float* rp = tables + ((long)srow * VOCAB + idxv[li + 1]) * EMB + half * 8;
                #pragma unroll
                for (int t = 0; t < 4; ++t) {
                    Na[t] = *(const f32x4*)(rp + t * 16);
                    Nb[t] = *(const f32x4*)(rp + t * 16 + 4);
                }
            }
            f32x16 acc = {};
            #pragma unroll
            for (int t = 0; t < 4; ++t) {
                bf16x8 f;
                #pragma unroll
                for (int j = 0; j < 4; ++j) f[j] = f2bf(Ca[t][j]);
                #pragma unroll
                for (int j = 0; j < 4; ++j) f[4 + j] = f2bf(Cb[t][j]);
                acc = __builtin_amdgcn_mfma_f32_32x32x16_bf16(f, f, acc, 0, 0, 0);
            }
            int c = row;
            if (c < NSPARSE) {
                #pragma unroll
                for (int reg = 0; reg < 16; ++reg) {
                    int r = (reg & 3) + 8 * (reg >> 2) + 4 * half;
                    if (r < c) {
                        int p = r * (2 * NSPARSE - r - 1) / 2 + (c - r - 1);
                        As[(w * 4 + li) * ASTR + 64 + p] = f2bf(acc[reg]);
                    }
                }
            }
            #pragma unroll
            for (int t = 0; t < 4; ++t) { Ca[t] = Na[t]; Cb[t] = Nb[t]; }
        }
    };

    // ---- MLP chain: 16 rows; wave w owns N-quarter ----
    auto mlp_phase = [&]() {
        // phase 0: X1 = relu(Ds @ W0^T + b0): 16x512, K=32, B from global
        {
            bf16x8 a = *(const bf16x8*)&Ds[lr * 32 + lg * 8];
            f32x4 acc[8] = {};
            #pragma unroll
            for (int ni = 0; ni < 8; ++ni) {
                bf16x8 b = *(const bf16x8*)(W0t + (size_t)(w * 128 + ni * 16 + lr) * 32 + lg * 8);
                acc[ni] = __builtin_amdgcn_mfma_f32_16x16x32_bf16(a, b, acc[ni], 0, 0, 0);
            }
            #pragma unroll
            for (int ni = 0; ni < 8; ++ni) {
                int col = w * 128 + ni * 16 + lr;
                float bv = b0[col];
                #pragma unroll
                for (int j = 0; j < 4; ++j)
                    X1s[(lg * 4 + j) * X1STR + col] = f2bf(fmaxf(acc[ni][j] + bv, 0.f));
            }
        }
        // phase 1: X2 = relu(X1 @ W1^T + b1): 16x256, K=512, dbuf single-sync
        stage256(Bst[0], W1t, 512, 0);
        __syncthreads();   // X1s visible + buf0 ready
        {
            f32x4 acc[4] = {};
            int s = 0;
            for (int k0 = 0; k0 < 512; k0 += 32, s ^= 1) {
                if (k0 + 32 < 512) stage256(Bst[s ^ 1], W1t, 512, k0 + 32);
                bf16x8 a = *(const bf16x8*)&X1s[lr * X1STR + k0 + lg * 8];
                #pragma unroll
                for (int ni = 0; ni < 4; ++ni) {
                    int n = w * 64 + ni * 16 + lr;
                    bf16x8 b = *(const bf16x8*)&Bst[s][n * 32 + swz];
                    acc[ni] = __builtin_amdgcn_mfma_f32_16x16x32_bf16(a, b, acc[ni], 0, 0, 0);
                }
                __syncthreads();
            }
            #pragma unroll
            for (int ni = 0; ni < 4; ++ni) {
                int col = w * 64 + ni * 16 + lr;
                float bv = b1[col];
                #pragma unroll
                for (int j = 0; j < 4; ++j)
                    X2s[(lg * 4 + j) * X2STR + col] = f2bf(fmaxf(acc[ni][j] + bv, 0.f));
            }
        }
        // phase 2: dense_out -> As cols 0..63: 16x64, K=256, dbuf single-sync
        stage64(Bst[0], W2t, 256, 0);
        __syncthreads();
        {
            f32x4 acc = {};
            int s = 0;
            for (int k0 = 0; k0 < 256; k0 += 32, s ^= 1) {
                if (k0 + 32 < 256) stage64(Bst[s ^ 1], W2t, 256, k0 + 32);
                bf16x8 a = *(const bf16x8*)&X2s[lr * X2STR + k0 + lg * 8];
                int n = w * 16 + lr;
                bf16x8 b = *(const bf16x8*)&Bst[s][n * 32 + swz];
                acc = __builtin_amdgcn_mfma_f32_16x16x32_bf16(a, b, acc, 0, 0, 0);
                __syncthreads();
            }
            int col = w * 16 + lr;
            float bv = b2[col];
            #pragma unroll
            for (int j = 0; j < 4; ++j)
                As[(lg * 4 + j) * ASTR + col] = f2bf(fmaxf(acc[j] + bv, 0.f));
        }
    };

    // stagger co-resident blocks' phase order (neutral historically; cheap)
    if ((blockIdx.x >> 9) & 1) { mlp_phase(); gram_phase(); }
    else                       { gram_phase(); mlp_phase(); }

    // ---- top GEMM: out(16x256) = As(16xK416) @ Wtt^T + bt, dbuf ----
    stage256(Bst[0], Wtt, KTOP, 0);
    __syncthreads();   // As (gram + dense) visible + buf0 ready
    {
        f32x4 acc[4] = {};
        int s = 0;
        for (int k0 = 0; k0 < KTOP; k0 += 32, s ^= 1) {
            if (k0 + 32 < KTOP) stage256(Bst[s ^ 1], Wtt, KTOP, k0 + 32);
            bf16x8 a = *(const bf16x8*)&As[lr * ASTR + k0 + lg * 8];
            #pragma unroll
            for (int ni = 0; ni < 4; ++ni) {
                int n = w * 64 + ni * 16 + lr;
                bf16x8 b = *(const bf16x8*)&Bst[s][n * 32 + swz];
                acc[ni] = __builtin_amdgcn_mfma_f32_16x16x32_bf16(a, b, acc[ni], 0, 0, 0);
            }
            __syncthreads();
        }
        #pragma unroll
        for (int ni = 0; ni < 4; ++ni) {
            int col = w * 64 + ni * 16 + lr;
            float bv = bt[col];
            #pragma unroll
            for (int j = 0; j < 4; ++j) {
                int r = lg * 4 + j;
                out[(size_t)(sbase + r) * 256 + col] = acc[ni][j] + bv;
            }
        }
    }
}

// -------------------------------------------------------------- launch ----
extern "C" void kernel_launch(void* const* d_in, const int* in_sizes, int n_in,
                              void* d_out, int out_size, void* d_ws, size_t ws_size,
                              hipStream_t stream)
{
    const float* dense  = (const float*)d_in[0];
    const int*   sparse = (const int*)  d_in[1];
    const float* tables = (const float*)d_in[2];
    const float* W0     = (const float*)d_in[3];
    const float* b0     = (const float*)d_in[4];
    const float* W1     = (const float*)d_in[5];
    const float* b1     = (const float*)d_in[6];
    const float* W2     = (const float*)d_in[7];
    const float* b2     = (const float*)d_in[8];
    const float* Wt     = (const float*)d_in[9];
    const float* bt     = (const float*)d_in[10];
    float* out = (float*)d_out;

    char* ws = (char*)d_ws;
    short* W0t = (short*)(ws);
    short* W1t = (short*)(ws + 32768);
    short* W2t = (short*)(ws + 294912);
    short* Wtt = (short*)(ws + 327680);

    prep_weights<<<264, 256, 0, stream>>>(W0, W1, W2, Wt, W0t, W1t, W2t, Wtt);

    fused_all<<<BATCH / SPB, 256, 0, stream>>>(sparse, tables, dense,
                                               W0t, b0, W1t, b1, W2t, b2,
                                               Wtt, bt, out);
}

// Round 11
// 54.459 us; speedup vs baseline: 1.1991x; 1.1991x over previous
//
#include <hip/hip_runtime.h>
#include <hip/hip_bf16.h>

// DLRM-like, round 11: r9 structure (SPB=32, 2 blocks/CU, best=52.0us) with
// the gram gather restructured as cooperative global_load_lds (fire-and-
// forget, ~27KB in flight per block vs 256B/wave register path).
// LDS gather buffer uses source-side XOR seg swizzle (dest stays linear,
// required by global_load_lds; read-side applies same involution).
//
// ws layout (bytes):
//   [0,      32768)   W0t 512x32  bf16 (k>=13 zero)
//   [32768,  294912)  W1t 256x512 bf16
//   [294912, 327680)  W2t 64x256  bf16
//   [327680, 540672)  Wtt 256x416 bf16 (k>=389 zero)

#define BATCH   16384
#define NSPARSE 26
#define VOCAB   100000
#define EMB     64
#define KTOP    416
#define KREAL   389
#define SPB     32
#define ASTR    424   // shorts
#define X1STR   520
#define X2STR   264

typedef __attribute__((ext_vector_type(8)))  short bf16x8;
typedef __attribute__((ext_vector_type(4)))  short s16x4;
typedef __attribute__((ext_vector_type(4)))  float f32x4;
typedef __attribute__((ext_vector_type(16))) float f32x16;

__device__ inline void gload_lds16(const void* g, void* l) {
    __builtin_amdgcn_global_load_lds(
        (const __attribute__((address_space(1))) void*)g,
        (__attribute__((address_space(3))) void*)l, 16, 0, 0);
}

__device__ inline short f2bf(float x) {
    __hip_bfloat16 h = __float2bfloat16(x);
    return *reinterpret_cast<short*>(&h);
}

// ------------------------------------------------- prep: tiled transpose ----
__global__ __launch_bounds__(256)
void prep_weights(const float* __restrict__ W0, const float* __restrict__ W1,
                  const float* __restrict__ W2, const float* __restrict__ Wt,
                  short* __restrict__ W0t, short* __restrict__ W1t,
                  short* __restrict__ W2t, short* __restrict__ Wtt)
{
    __shared__ float tile[32][36];
    int b = blockIdx.x, t = threadIdx.x;
    const float* src; short* dst; int K, N, Kpad, k0, n0;
    if (b < 16)        {              src = W0; dst = W0t; K = 13;  N = 512; Kpad = 32;  k0 = 0;           n0 = b * 32; }
    else if (b < 144)  { int i = b - 16;  src = W1; dst = W1t; K = 512; N = 256; Kpad = 512; k0 = (i >> 3) * 32; n0 = (i & 7) * 32; }
    else if (b < 160)  { int i = b - 144; src = W2; dst = W2t; K = 256; N = 64;  Kpad = 256; k0 = (i >> 1) * 32; n0 = (i & 1) * 32; }
    else               { int i = b - 160; src = Wt; dst = Wtt; K = 389; N = 256; Kpad = 416; k0 = (i >> 3) * 32; n0 = (i & 7) * 32; }

    int r = t >> 3, c4 = (t & 7) * 4;
    int gr = k0 + r;
    float4 v = make_float4(0.f, 0.f, 0.f, 0.f);
    if (gr < K) v = *(const float4*)(src + (size_t)gr * N + n0 + c4);
    tile[r][c4 + 0] = v.x; tile[r][c4 + 1] = v.y;
    tile[r][c4 + 2] = v.z; tile[r][c4 + 3] = v.w;
    __syncthreads();
    s16x4 o;
    #pragma unroll
    for (int j = 0; j < 4; ++j) o[j] = f2bf(tile[c4 + j][r]);
    *(s16x4*)&dst[(size_t)(n0 + r) * Kpad + k0 + c4] = o;
}

// ------------------------------------------------------------ megakernel ----
__global__ __launch_bounds__(256, 2)
void fused_all(const int* __restrict__ sparse, const float* __restrict__ tables,
               const float* __restrict__ D,
               const short* __restrict__ W0t, const float* __restrict__ b0,
               const short* __restrict__ W1t, const float* __restrict__ b1,
               const short* __restrict__ W2t, const float* __restrict__ b2,
               const short* __restrict__ Wtt, const float* __restrict__ bt,
               float* __restrict__ out)
{
    // As 27136 | X1s 33280 (gram gather buf aliases; X2s aliases)
    // | Bst 16384 | Ds 2048 = 78848 B total -> 2 blocks/CU
    __shared__ __align__(16) char smem[78848];
    short* As   = (short*)(smem);
    short* X1s  = (short*)(smem + 27136);
    short* X2s  = (short*)(smem + 27136);
    float* gbuf = (float*)(smem + 27136);    // 4 samples x 26 rows x 256B = 26624
    int*  idxb  = (int*)  (smem + 53760);    // 32 x 26 x 4B = 3328
    short* Bst  = (short*)(smem + 60416);
    short* Ds   = (short*)(smem + 76800);

    int tid = threadIdx.x;
    int w = tid >> 6, lane = tid & 63;
    int lr = lane & 15, lg = lane >> 4;
    int wr = w >> 1, wc = w & 1;
    int swz = (lg ^ (lr & 3)) * 8;        // Bst read swizzle (matches source)
    int sbase = blockIdx.x * SPB;

    // stage indices, Ds (32x13 -> bf16 K=32 pad), zero As pad cols 389..415
    for (int x = tid; x < SPB * NSPARSE; x += 256)
        idxb[x] = sparse[(size_t)sbase * NSPARSE + x];
    for (int x = tid; x < SPB * 13; x += 256) {
        int r = x / 13, k = x - r * 13;
        Ds[r * 32 + k] = f2bf(D[(size_t)sbase * 13 + x]);
    }
    for (int x = tid; x < SPB * 19; x += 256) {
        int r = x / 19, k = 13 + (x - r * 19);
        Ds[r * 32 + k] = 0;
    }
    for (int x = tid; x < SPB * 27; x += 256) {
        int r = x / 27, c = x - r * 27;
        As[r * ASTR + KREAL + c] = 0;
    }
    __syncthreads();

    // ---- gram: 8 groups of 4 samples; cooperative gload_lds gather ----
    // chunk c (0..1663): sl=c/416, r=(c%416)/16, s=c%16.
    // LDS slot s holds source seg s^(r&7) (involution; dest stays linear).
    {
        int row = lane & 31, half = lane >> 5;
        int srow = (row < NSPARSE) ? row : 0;
        int x7 = srow & 7;
        const float* myrow = gbuf + srow * 64;   // + sample*1664 at use

        for (int g = 0; g < 8; ++g) {
            #pragma unroll
            for (int it = 0; it < 7; ++it) {
                int c = it * 256 + tid;
                if (c < 1664) {
                    int sl = c / 416, rem = c - sl * 416;
                    int r = rem >> 4, s = rem & 15;
                    int idx = idxb[(g * 4 + sl) * NSPARSE + r];
                    const float* src = tables + ((long)r * VOCAB + idx) * EMB
                                       + (s ^ (r & 7)) * 4;
                    gload_lds16(src, (char*)gbuf + c * 16);
                }
            }
            __syncthreads();   // drains vmcnt -> gbuf ready

            // wave w computes gram of sample g*4+w from LDS
            const float* sp = myrow + w * 1664;
            f32x16 acc = {};
            #pragma unroll
            for (int t = 0; t < 4; ++t) {
                int s0 = half * 2 + t * 4;
                f32x4 ca = *(const f32x4*)(sp + (s0 ^ x7) * 4);
                f32x4 cb = *(const f32x4*)(sp + ((s0 + 1) ^ x7) * 4);
                bf16x8 f;
                #pragma unroll
                for (int j = 0; j < 4; ++j) f[j] = f2bf(ca[j]);
                #pragma unroll
                for (int j = 0; j < 4; ++j) f[4 + j] = f2bf(cb[j]);
                acc = __builtin_amdgcn_mfma_f32_32x32x16_bf16(f, f, acc, 0, 0, 0);
            }
            int c = row;
            if (c < NSPARSE) {
                #pragma unroll
                for (int reg = 0; reg < 16; ++reg) {
                    int r = (reg & 3) + 8 * (reg >> 2) + 4 * half;
                    if (r < c) {
                        int p = r * (2 * NSPARSE - r - 1) / 2 + (c - r - 1);
                        As[(g * 4 + w) * ASTR + 64 + p] = f2bf(acc[reg]);
                    }
                }
            }
            __syncthreads();   // gbuf reusable
        }
    }

    // ---- MLP chain (r9 structure, verbatim) ----
    {
        // phase 0: X1 = relu(Ds @ W0^T + b0): 32x512, K=32
        {
            bf16x8 a = *(const bf16x8*)&Ds[(wr * 16 + lr) * 32 + lg * 8];
            f32x4 acc[16] = {};
            #pragma unroll
            for (int ni = 0; ni < 16; ++ni) {
                bf16x8 b = *(const bf16x8*)(W0t + (size_t)(wc * 256 + ni * 16 + lr) * 32 + lg * 8);
                acc[ni] = __builtin_amdgcn_mfma_f32_16x16x32_bf16(a, b, acc[ni], 0, 0, 0);
            }
            #pragma unroll
            for (int ni = 0; ni < 16; ++ni) {
                int col = wc * 256 + ni * 16 + lr;
                float bv = b0[col];
                #pragma unroll
                for (int j = 0; j < 4; ++j) {
                    int r = wr * 16 + lg * 4 + j;
                    X1s[r * X1STR + col] = f2bf(fmaxf(acc[ni][j] + bv, 0.f));
                }
            }
        }
        __syncthreads();
        // phase 1: X2 = relu(X1 @ W1^T + b1): 32x256, K=512
        {
            f32x4 acc[8] = {};
            for (int k0 = 0; k0 < 512; k0 += 32) {
                #pragma unroll
                for (int rd = 0; rd < 4; ++rd) {
                    int slot = rd * 256 + tid;
                    int n = slot >> 2, kc = slot & 3;
                    gload_lds16(W1t + (size_t)n * 512 + k0 + (kc ^ (n & 3)) * 8, &Bst[slot * 8]);
                }
                __syncthreads();
                bf16x8 a = *(const bf16x8*)&X1s[(wr * 16 + lr) * X1STR + k0 + lg * 8];
                #pragma unroll
                for (int ni = 0; ni < 8; ++ni) {
                    int n = wc * 128 + ni * 16 + lr;
                    bf16x8 b = *(const bf16x8*)&Bst[n * 32 + swz];
                    acc[ni] = __builtin_amdgcn_mfma_f32_16x16x32_bf16(a, b, acc[ni], 0, 0, 0);
                }
                __syncthreads();
            }
            #pragma unroll
            for (int ni = 0; ni < 8; ++ni) {
                int col = wc * 128 + ni * 16 + lr;
                float bv = b1[col];
                #pragma unroll
                for (int j = 0; j < 4; ++j) {
                    int r = wr * 16 + lg * 4 + j;
                    X2s[r * X2STR + col] = f2bf(fmaxf(acc[ni][j] + bv, 0.f));
                }
            }
        }
        __syncthreads();
        // phase 2: dense_out -> As cols 0..63: 32x64, K=256
        {
            f32x4 acc[2] = {};
            for (int k0 = 0; k0 < 256; k0 += 32) {
                {
                    int n = tid >> 2, kc = tid & 3;
                    gload_lds16(W2t + (size_t)n * 256 + k0 + (kc ^ (n & 3)) * 8, &Bst[tid * 8]);
                }
                __syncthreads();
                bf16x8 a = *(const bf16x8*)&X2s[(wr * 16 + lr) * X2STR + k0 + lg * 8];
                #pragma unroll
                for (int ni = 0; ni < 2; ++ni) {
                    int n = wc * 32 + ni * 16 + lr;
                    bf16x8 b = *(const bf16x8*)&Bst[n * 32 + swz];
                    acc[ni] = __builtin_amdgcn_mfma_f32_16x16x32_bf16(a, b, acc[ni], 0, 0, 0);
                }
                __syncthreads();
            }
            #pragma unroll
            for (int ni = 0; ni < 2; ++ni) {
                int col = wc * 32 + ni * 16 + lr;
                float bv = b2[col];
                #pragma unroll
                for (int j = 0; j < 4; ++j) {
                    int r = wr * 16 + lg * 4 + j;
                    As[r * ASTR + col] = f2bf(fmaxf(acc[ni][j] + bv, 0.f));
                }
            }
        }
        __syncthreads();
    }

    // ---- top GEMM: out(32x256) = As(32xK416) @ Wtt^T + bt ----
    {
        f32x4 acc[8] = {};
        for (int k0 = 0; k0 < KTOP; k0 += 32) {
            #pragma unroll
            for (int rd = 0; rd < 4; ++rd) {
                int slot = rd * 256 + tid;
                int n = slot >> 2, kc = slot & 3;
                gload_lds16(Wtt + (size_t)n * KTOP + k0 + (kc ^ (n & 3)) * 8, &Bst[slot * 8]);
            }
            __syncthreads();
            bf16x8 a = *(const bf16x8*)&As[(wr * 16 + lr) * ASTR + k0 + lg * 8];
            #pragma unroll
            for (int ni = 0; ni < 8; ++ni) {
                int n = wc * 128 + ni * 16 + lr;
                bf16x8 b = *(const bf16x8*)&Bst[n * 32 + swz];
                acc[ni] = __builtin_amdgcn_mfma_f32_16x16x32_bf16(a, b, acc[ni], 0, 0, 0);
            }
            __syncthreads();
        }
        #pragma unroll
        for (int ni = 0; ni < 8; ++ni) {
            int col = wc * 128 + ni * 16 + lr;
            float bv = bt[col];
            #pragma unroll
            for (int j = 0; j < 4; ++j) {
                int r = wr * 16 + lg * 4 + j;
                out[(size_t)(sbase + r) * 256 + col] = acc[ni][j] + bv;
            }
        }
    }
}

// -------------------------------------------------------------- launch ----
extern "C" void kernel_launch(void* const* d_in, const int* in_sizes, int n_in,
                              void* d_out, int out_size, void* d_ws, size_t ws_size,
                              hipStream_t stream)
{
    const float* dense  = (const float*)d_in[0];
    const int*   sparse = (const int*)  d_in[1];
    const float* tables = (const float*)d_in[2];
    const float* W0     = (const float*)d_in[3];
    const float* b0     = (const float*)d_in[4];
    const float* W1     = (const float*)d_in[5];
    const float* b1     = (const float*)d_in[6];
    const float* W2     = (const float*)d_in[7];
    const float* b2     = (const float*)d_in[8];
    const float* Wt     = (const float*)d_in[9];
    const float* bt     = (const float*)d_in[10];
    float* out = (float*)d_out;

    char* ws = (char*)d_ws;
    short* W0t = (short*)(ws);
    short* W1t = (short*)(ws + 32768);
    short* W2t = (short*)(ws + 294912);
    short* Wtt = (short*)(ws + 327680);

    prep_weights<<<264, 256, 0, stream>>>(W0, W1, W2, Wt, W0t, W1t, W2t, Wtt);

    fused_all<<<BATCH / SPB, 256, 0, stream>>>(sparse, tables, dense,
                                               W0t, b0, W1t, b1, W2t, b2,
                                               Wtt, bt, out);
}

// Round 12
// 48.133 us; speedup vs baseline: 1.3567x; 1.1314x over previous
//
#include <hip/hip_runtime.h>
#include <hip/hip_bf16.h>

// DLRM-like, round 12: SPB=64 megakernel (256 blocks = 1/CU, 512 threads)
// to HALVE weight-restage VMEM traffic (the dominant byte term), with
// double-buffered single-sync K-loops (stage(next); compute(cur); sync).
//
// ws layout (bytes):
//   [0,      32768)   W0t 512x32  bf16 (k>=13 zero)
//   [32768,  294912)  W1t 256x512 bf16
//   [294912, 327680)  W2t 64x256  bf16
//   [327680, 540672)  Wtt 256x416 bf16 (k>=389 zero)

#define BATCH   16384
#define NSPARSE 26
#define VOCAB   100000
#define EMB     64
#define KTOP    416
#define KREAL   389
#define SPB     64
#define ASTR    424   // shorts
#define X1STR   520
#define X2STR   264

typedef __attribute__((ext_vector_type(8)))  short bf16x8;
typedef __attribute__((ext_vector_type(4)))  short s16x4;
typedef __attribute__((ext_vector_type(4)))  float f32x4;
typedef __attribute__((ext_vector_type(16))) float f32x16;

__device__ inline void gload_lds16(const void* g, void* l) {
    __builtin_amdgcn_global_load_lds(
        (const __attribute__((address_space(1))) void*)g,
        (__attribute__((address_space(3))) void*)l, 16, 0, 0);
}

__device__ inline short f2bf(float x) {
    __hip_bfloat16 h = __float2bfloat16(x);
    return *reinterpret_cast<short*>(&h);
}

// ------------------------------------------------- prep: tiled transpose ----
__global__ __launch_bounds__(256)
void prep_weights(const float* __restrict__ W0, const float* __restrict__ W1,
                  const float* __restrict__ W2, const float* __restrict__ Wt,
                  short* __restrict__ W0t, short* __restrict__ W1t,
                  short* __restrict__ W2t, short* __restrict__ Wtt)
{
    __shared__ float tile[32][36];
    int b = blockIdx.x, t = threadIdx.x;
    const float* src; short* dst; int K, N, Kpad, k0, n0;
    if (b < 16)        {              src = W0; dst = W0t; K = 13;  N = 512; Kpad = 32;  k0 = 0;           n0 = b * 32; }
    else if (b < 144)  { int i = b - 16;  src = W1; dst = W1t; K = 512; N = 256; Kpad = 512; k0 = (i >> 3) * 32; n0 = (i & 7) * 32; }
    else if (b < 160)  { int i = b - 144; src = W2; dst = W2t; K = 256; N = 64;  Kpad = 256; k0 = (i >> 1) * 32; n0 = (i & 1) * 32; }
    else               { int i = b - 160; src = Wt; dst = Wtt; K = 389; N = 256; Kpad = 416; k0 = (i >> 3) * 32; n0 = (i & 7) * 32; }

    int r = t >> 3, c4 = (t & 7) * 4;
    int gr = k0 + r;
    float4 v = make_float4(0.f, 0.f, 0.f, 0.f);
    if (gr < K) v = *(const float4*)(src + (size_t)gr * N + n0 + c4);
    tile[r][c4 + 0] = v.x; tile[r][c4 + 1] = v.y;
    tile[r][c4 + 2] = v.z; tile[r][c4 + 3] = v.w;
    __syncthreads();
    s16x4 o;
    #pragma unroll
    for (int j = 0; j < 4; ++j) o[j] = f2bf(tile[c4 + j][r]);
    *(s16x4*)&dst[(size_t)(n0 + r) * Kpad + k0 + c4] = o;
}

// ------------------------------------------------------------ megakernel ----
__global__ __launch_bounds__(512, 1)
void fused_all(const int* __restrict__ sparse, const float* __restrict__ tables,
               const float* __restrict__ D,
               const short* __restrict__ W0t, const float* __restrict__ b0,
               const short* __restrict__ W1t, const float* __restrict__ b1,
               const short* __restrict__ W2t, const float* __restrict__ b2,
               const short* __restrict__ Wtt, const float* __restrict__ bt,
               float* __restrict__ out)
{
    // Ds 4K | As 54.25K | X1s 66.5K (X2s aliases) | Bst0 16K | Bst1 16K
    __shared__ __align__(16) char smem[157696];
    short* Ds   = (short*)(smem);
    short* As   = (short*)(smem + 4096);
    short* X1s  = (short*)(smem + 58368);
    short* X2s  = (short*)(smem + 58368);   // alias: X1s dead after phase-1 loop
    short* Bst0 = (short*)(smem + 124928);
    short* Bst1 = (short*)(smem + 141312);
    short* bufs[2] = {Bst0, Bst1};

    int tid = threadIdx.x;
    int w = tid >> 6, lane = tid & 63;
    int lr = lane & 15, lg = lane >> 4;
    int wr = w >> 2, wc = w & 3;           // 2 M-halves x 4 N-quarters
    int swz = (lg ^ (lr & 3)) * 8;         // matches source kc^(n&3) pre-swizzle
    int sbase = blockIdx.x * SPB;

    auto stage256 = [&](short* dstBuf, const short* W, int ldw, int k0) {
        #pragma unroll
        for (int rd = 0; rd < 2; ++rd) {
            int slot = rd * 512 + tid;
            int n = slot >> 2, kc = slot & 3;
            gload_lds16(W + (size_t)n * ldw + k0 + (kc ^ (n & 3)) * 8,
                        dstBuf + slot * 8);
        }
    };
    auto stage64 = [&](short* dstBuf, const short* W, int ldw, int k0) {
        if (tid < 256) {
            int n = tid >> 2, kc = tid & 3;
            gload_lds16(W + (size_t)n * ldw + k0 + (kc ^ (n & 3)) * 8,
                        dstBuf + tid * 8);
        }
    };

    // init: Ds (64x13 f32 -> bf16 K=32 pad), zero As pad cols 389..415
    for (int x = tid; x < SPB * 13; x += 512) {
        int r = x / 13, k = x - r * 13;
        Ds[r * 32 + k] = f2bf(D[(size_t)sbase * 13 + x]);
    }
    for (int x = tid; x < SPB * 19; x += 512) {
        int r = x / 19, k = 13 + (x - r * 19);
        Ds[r * 32 + k] = 0;
    }
    for (int x = tid; x < SPB * 27; x += 512) {
        int r = x / 27, c = x - r * 27;
        As[r * ASTR + KREAL + c] = 0;
    }
    __syncthreads();

    // ---- gram: wave w -> samples w*8..w*8+7, 2-deep register pipeline ----
    {
        int row = lane & 31, half = lane >> 5;
        int srow = (row < NSPARSE) ? row : 0;   // lanes>=26 dup row 0; garbage
        int idxv[8];                            // lands in r,c>=26 only
        #pragma unroll
        for (int li = 0; li < 8; ++li)
            idxv[li] = sparse[(sbase + w * 8 + li) * NSPARSE + srow];

        f32x4 Ca[4], Cb[4], Na[4], Nb[4];
        {
            const float* rp = tables + ((long)srow * VOCAB + idxv[0]) * EMB + half * 8;
            #pragma unroll
            for (int t = 0; t < 4; ++t) {
                Ca[t] = *(const f32x4*)(rp + t * 16);
                Cb[t] = *(const f32x4*)(rp + t * 16 + 4);
            }
        }
        #pragma unroll
        for (int li = 0; li < 8; ++li) {
            if (li < 7) {
                const float* rp = tables + ((long)srow * VOCAB + idxv[li + 1]) * EMB + half * 8;
                #pragma unroll
                for (int t = 0; t < 4; ++t) {
                    Na[t] = *(const f32x4*)(rp + t * 16);
                    Nb[t] = *(const f32x4*)(rp + t * 16 + 4);
                }
            }
            f32x16 acc = {};
            #pragma unroll
            for (int t = 0; t < 4; ++t) {
                bf16x8 f;
                #pragma unroll
                for (int j = 0; j < 4; ++j) f[j] = f2bf(Ca[t][j]);
                #pragma unroll
                for (int j = 0; j < 4; ++j) f[4 + j] = f2bf(Cb[t][j]);
                acc = __builtin_amdgcn_mfma_f32_32x32x16_bf16(f, f, acc, 0, 0, 0);
            }
            int c = row;
            if (c < NSPARSE) {
                #pragma unroll
                for (int reg = 0; reg < 16; ++reg) {
                    int r = (reg & 3) + 8 * (reg >> 2) + 4 * half;
                    if (r < c) {
                        int p = r * (2 * NSPARSE - r - 1) / 2 + (c - r - 1);
                        As[(w * 8 + li) * ASTR + 64 + p] = f2bf(acc[reg]);
                    }
                }
            }
            #pragma unroll
            for (int t = 0; t < 4; ++t) { Ca[t] = Na[t]; Cb[t] = Nb[t]; }
        }
    }

    // ---- phase 0: X1 = relu(Ds @ W0^T + b0): 64x512, K=32 (B from global) ----
    {
        bf16x8 a0 = *(const bf16x8*)&Ds[(wr * 32 + lr) * 32 + lg * 8];
        bf16x8 a1 = *(const bf16x8*)&Ds[(wr * 32 + 16 + lr) * 32 + lg * 8];
        f32x4 acc[2][8] = {};
        #pragma unroll
        for (int ni = 0; ni < 8; ++ni) {
            bf16x8 b = *(const bf16x8*)(W0t + (size_t)(wc * 128 + ni * 16 + lr) * 32 + lg * 8);
            acc[0][ni] = __builtin_amdgcn_mfma_f32_16x16x32_bf16(a0, b, acc[0][ni], 0, 0, 0);
            acc[1][ni] = __builtin_amdgcn_mfma_f32_16x16x32_bf16(a1, b, acc[1][ni], 0, 0, 0);
        }
        #pragma unroll
        for (int ni = 0; ni < 8; ++ni) {
            int col = wc * 128 + ni * 16 + lr;
            float bv = b0[col];
            #pragma unroll
            for (int mi = 0; mi < 2; ++mi)
                #pragma unroll
                for (int j = 0; j < 4; ++j) {
                    int r = wr * 32 + mi * 16 + lg * 4 + j;
                    X1s[r * X1STR + col] = f2bf(fmaxf(acc[mi][ni][j] + bv, 0.f));
                }
        }
    }

    // ---- phase 1: X2 = relu(X1 @ W1^T + b1): 64x256, K=512, dbuf ----
    stage256(bufs[0], W1t, 512, 0);
    __syncthreads();   // X1s visible + buf0 ready
    {
        f32x4 acc[2][4] = {};
        int s = 0;
        for (int k0 = 0; k0 < 512; k0 += 32, s ^= 1) {
            if (k0 + 32 < 512) stage256(bufs[s ^ 1], W1t, 512, k0 + 32);
            bf16x8 a0 = *(const bf16x8*)&X1s[(wr * 32 + lr) * X1STR + k0 + lg * 8];
            bf16x8 a1 = *(const bf16x8*)&X1s[(wr * 32 + 16 + lr) * X1STR + k0 + lg * 8];
            #pragma unroll
            for (int ni = 0; ni < 4; ++ni) {
                int n = wc * 64 + ni * 16 + lr;
                bf16x8 b = *(const bf16x8*)&bufs[s][n * 32 + swz];
                acc[0][ni] = __builtin_amdgcn_mfma_f32_16x16x32_bf16(a0, b, acc[0][ni], 0, 0, 0);
                acc[1][ni] = __builtin_amdgcn_mfma_f32_16x16x32_bf16(a1, b, acc[1][ni], 0, 0, 0);
            }
            __syncthreads();
        }
        #pragma unroll
        for (int ni = 0; ni < 4; ++ni) {
            int col = wc * 64 + ni * 16 + lr;
            float bv = b1[col];
            #pragma unroll
            for (int mi = 0; mi < 2; ++mi)
                #pragma unroll
                for (int j = 0; j < 4; ++j) {
                    int r = wr * 32 + mi * 16 + lg * 4 + j;
                    X2s[r * X2STR + col] = f2bf(fmaxf(acc[mi][ni][j] + bv, 0.f));
                }
        }
    }

    // ---- phase 2: dense_out -> As cols 0..63: 64x64, K=256, dbuf ----
    stage64(bufs[0], W2t, 256, 0);
    __syncthreads();   // X2s visible + buf0 ready
    {
        f32x4 acc[2] = {};
        int s = 0;
        for (int k0 = 0; k0 < 256; k0 += 32, s ^= 1) {
            if (k0 + 32 < 256) stage64(bufs[s ^ 1], W2t, 256, k0 + 32);
            bf16x8 a0 = *(const bf16x8*)&X2s[(wr * 32 + lr) * X2STR + k0 + lg * 8];
            bf16x8 a1 = *(const bf16x8*)&X2s[(wr * 32 + 16 + lr) * X2STR + k0 + lg * 8];
            int n = wc * 16 + lr;
            bf16x8 b = *(const bf16x8*)&bufs[s][n * 32 + swz];
            acc[0] = __builtin_amdgcn_mfma_f32_16x16x32_bf16(a0, b, acc[0], 0, 0, 0);
            acc[1] = __builtin_amdgcn_mfma_f32_16x16x32_bf16(a1, b, acc[1], 0, 0, 0);
            __syncthreads();
        }
        int col = wc * 16 + lr;
        float bv = b2[col];
        #pragma unroll
        for (int mi = 0; mi < 2; ++mi)
            #pragma unroll
            for (int j = 0; j < 4; ++j) {
                int r = wr * 32 + mi * 16 + lg * 4 + j;
                As[r * ASTR + col] = f2bf(fmaxf(acc[mi][j] + bv, 0.f));
            }
    }

    // ---- top GEMM: out(64x256) = As(64xK416) @ Wtt^T + bt, dbuf ----
    stage256(bufs[0], Wtt, KTOP, 0);
    __syncthreads();   // As (gram + dense) visible + buf0 ready
    {
        f32x4 acc[2][4] = {};
        int s = 0;
        for (int k0 = 0; k0 < KTOP; k0 += 32, s ^= 1) {
            if (k0 + 32 < KTOP) stage256(bufs[s ^ 1], Wtt, KTOP, k0 + 32);
            bf16x8 a0 = *(const bf16x8*)&As[(wr * 32 + lr) * ASTR + k0 + lg * 8];
            bf16x8 a1 = *(const bf16x8*)&As[(wr * 32 + 16 + lr) * ASTR + k0 + lg * 8];
            #pragma unroll
            for (int ni = 0; ni < 4; ++ni) {
                int n = wc * 64 + ni * 16 + lr;
                bf16x8 b = *(const bf16x8*)&bufs[s][n * 32 + swz];
                acc[0][ni] = __builtin_amdgcn_mfma_f32_16x16x32_bf16(a0, b, acc[0][ni], 0, 0, 0);
                acc[1][ni] = __builtin_amdgcn_mfma_f32_16x16x32_bf16(a1, b, acc[1][ni], 0, 0, 0);
            }
            __syncthreads();
        }
        #pragma unroll
        for (int ni = 0; ni < 4; ++ni) {
            int col = wc * 64 + ni * 16 + lr;
            float bv = bt[col];
            #pragma unroll
            for (int mi = 0; mi < 2; ++mi)
                #pragma unroll
                for (int j = 0; j < 4; ++j) {
                    int r = wr * 32 + mi * 16 + lg * 4 + j;
                    out[(size_t)(sbase + r) * 256 + col] = acc[mi][ni][j] + bv;
                }
        }
    }
}

// -------------------------------------------------------------- launch ----
extern "C" void kernel_launch(void* const* d_in, const int* in_sizes, int n_in,
                              void* d_out, int out_size, void* d_ws, size_t ws_size,
                              hipStream_t stream)
{
    const float* dense  = (const float*)d_in[0];
    const int*   sparse = (const int*)  d_in[1];
    const float* tables = (const float*)d_in[2];
    const float* W0     = (const float*)d_in[3];
    const float* b0     = (const float*)d_in[4];
    const float* W1     = (const float*)d_in[5];
    const float* b1     = (const float*)d_in[6];
    const float* W2     = (const float*)d_in[7];
    const float* b2     = (const float*)d_in[8];
    const float* Wt     = (const float*)d_in[9];
    const float* bt     = (const float*)d_in[10];
    float* out = (float*)d_out;

    char* ws = (char*)d_ws;
    short* W0t = (short*)(ws);
    short* W1t = (short*)(ws + 32768);
    short* W2t = (short*)(ws + 294912);
    short* Wtt = (short*)(ws + 327680);

    prep_weights<<<264, 256, 0, stream>>>(W0, W1, W2, Wt, W0t, W1t, W2t, Wtt);

    fused_all<<<BATCH / SPB, 512, 0, stream>>>(sparse, tables, dense,
                                               W0t, b0, W1t, b1, W2t, b2,
                                               Wtt, bt, out);
}

// Round 13
// 45.473 us; speedup vs baseline: 1.4361x; 1.0585x over previous
//
#include <hip/hip_runtime.h>
#include <hip/hip_bf16.h>

// DLRM-like, round 13: r12 (SPB=64, 1 block/CU, 512 thr) + counted-vmcnt
// 3-buffer K-loops (raw s_barrier, never vmcnt(0) mid-loop) so weight-stage
// latency hides 2 steps deep. As aliases dead X1s region (gram after phase1).
//
// ws layout (bytes):
//   [0,      32768)   W0t 512x32  bf16 (k>=13 zero)
//   [32768,  294912)  W1t 256x512 bf16
//   [294912, 327680)  W2t 64x256  bf16
//   [327680, 540672)  Wtt 256x416 bf16 (k>=389 zero)

#define BATCH   16384
#define NSPARSE 26
#define VOCAB   100000
#define EMB     64
#define KTOP    416
#define KREAL   389
#define SPB     64
#define ASTR    424   // shorts
#define X1STR   520
#define X2STR   264

#define WAIT_VMCNT(N) asm volatile("s_waitcnt vmcnt(" #N ")" ::: "memory")

typedef __attribute__((ext_vector_type(8)))  short bf16x8;
typedef __attribute__((ext_vector_type(4)))  short s16x4;
typedef __attribute__((ext_vector_type(4)))  float f32x4;
typedef __attribute__((ext_vector_type(16))) float f32x16;

__device__ inline void gload_lds16(const void* g, void* l) {
    __builtin_amdgcn_global_load_lds(
        (const __attribute__((address_space(1))) void*)g,
        (__attribute__((address_space(3))) void*)l, 16, 0, 0);
}

__device__ inline short f2bf(float x) {
    __hip_bfloat16 h = __float2bfloat16(x);
    return *reinterpret_cast<short*>(&h);
}

// ------------------------------------------------- prep: tiled transpose ----
__global__ __launch_bounds__(256)
void prep_weights(const float* __restrict__ W0, const float* __restrict__ W1,
                  const float* __restrict__ W2, const float* __restrict__ Wt,
                  short* __restrict__ W0t, short* __restrict__ W1t,
                  short* __restrict__ W2t, short* __restrict__ Wtt)
{
    __shared__ float tile[32][36];
    int b = blockIdx.x, t = threadIdx.x;
    const float* src; short* dst; int K, N, Kpad, k0, n0;
    if (b < 16)        {              src = W0; dst = W0t; K = 13;  N = 512; Kpad = 32;  k0 = 0;           n0 = b * 32; }
    else if (b < 144)  { int i = b - 16;  src = W1; dst = W1t; K = 512; N = 256; Kpad = 512; k0 = (i >> 3) * 32; n0 = (i & 7) * 32; }
    else if (b < 160)  { int i = b - 144; src = W2; dst = W2t; K = 256; N = 64;  Kpad = 256; k0 = (i >> 1) * 32; n0 = (i & 1) * 32; }
    else               { int i = b - 160; src = Wt; dst = Wtt; K = 389; N = 256; Kpad = 416; k0 = (i >> 3) * 32; n0 = (i & 7) * 32; }

    int r = t >> 3, c4 = (t & 7) * 4;
    int gr = k0 + r;
    float4 v = make_float4(0.f, 0.f, 0.f, 0.f);
    if (gr < K) v = *(const float4*)(src + (size_t)gr * N + n0 + c4);
    tile[r][c4 + 0] = v.x; tile[r][c4 + 1] = v.y;
    tile[r][c4 + 2] = v.z; tile[r][c4 + 3] = v.w;
    __syncthreads();
    s16x4 o;
    #pragma unroll
    for (int j = 0; j < 4; ++j) o[j] = f2bf(tile[c4 + j][r]);
    *(s16x4*)&dst[(size_t)(n0 + r) * Kpad + k0 + c4] = o;
}

// ------------------------------------------------------------ megakernel ----
__global__ __launch_bounds__(512, 1)
void fused_all(const int* __restrict__ sparse, const float* __restrict__ tables,
               const float* __restrict__ D,
               const short* __restrict__ W0t, const float* __restrict__ b0,
               const short* __restrict__ W1t, const float* __restrict__ b1,
               const short* __restrict__ W2t, const float* __restrict__ b2,
               const short* __restrict__ Wtt, const float* __restrict__ bt,
               float* __restrict__ out)
{
    // [0,66560) X1s, later As | [66560,100352) X2s | B0/B1/B2 16K each | Ds 4K
    __shared__ __align__(16) char smem[153600];
    short* X1s = (short*)(smem);
    short* As  = (short*)(smem);            // alias: X1s dead after phase 1
    short* X2s = (short*)(smem + 66560);
    short* B0  = (short*)(smem + 100352);
    short* B1  = (short*)(smem + 116736);
    short* B2  = (short*)(smem + 133120);
    short* Ds  = (short*)(smem + 149504);

    int tid = threadIdx.x;
    int w = tid >> 6, lane = tid & 63;
    int lr = lane & 15, lg = lane >> 4;
    int wr = w >> 2, wc = w & 3;           // 2 M-halves x 4 N-quarters
    int swz = (lg ^ (lr & 3)) * 8;         // matches source kc^(n&3) pre-swizzle
    int sbase = blockIdx.x * SPB;

    auto stage256 = [&](short* dstBuf, const short* W, int ldw, int k0) {
        #pragma unroll
        for (int rd = 0; rd < 2; ++rd) {
            int slot = rd * 512 + tid;
            int n = slot >> 2, kc = slot & 3;
            gload_lds16(W + (size_t)n * ldw + k0 + (kc ^ (n & 3)) * 8,
                        dstBuf + slot * 8);
        }
    };
    auto stage64 = [&](short* dstBuf, const short* W, int ldw, int k0) {
        if (tid < 256) {
            int n = tid >> 2, kc = tid & 3;
            gload_lds16(W + (size_t)n * ldw + k0 + (kc ^ (n & 3)) * 8,
                        dstBuf + tid * 8);
        }
    };

    // ---- init: Ds (64x13 f32 -> bf16, K=32 pad) ----
    for (int x = tid; x < SPB * 13; x += 512) {
        int r = x / 13, k = x - r * 13;
        Ds[r * 32 + k] = f2bf(D[(size_t)sbase * 13 + x]);
    }
    for (int x = tid; x < SPB * 19; x += 512) {
        int r = x / 19, k = 13 + (x - r * 19);
        Ds[r * 32 + k] = 0;
    }
    __syncthreads();

    // ---- phase 0: X1 = relu(Ds @ W0^T + b0): 64x512, K=32 (B from global) ----
    {
        bf16x8 a0 = *(const bf16x8*)&Ds[(wr * 32 + lr) * 32 + lg * 8];
        bf16x8 a1 = *(const bf16x8*)&Ds[(wr * 32 + 16 + lr) * 32 + lg * 8];
        f32x4 acc[2][8] = {};
        #pragma unroll
        for (int ni = 0; ni < 8; ++ni) {
            bf16x8 b = *(const bf16x8*)(W0t + (size_t)(wc * 128 + ni * 16 + lr) * 32 + lg * 8);
            acc[0][ni] = __builtin_amdgcn_mfma_f32_16x16x32_bf16(a0, b, acc[0][ni], 0, 0, 0);
            acc[1][ni] = __builtin_amdgcn_mfma_f32_16x16x32_bf16(a1, b, acc[1][ni], 0, 0, 0);
        }
        #pragma unroll
        for (int ni = 0; ni < 8; ++ni) {
            int col = wc * 128 + ni * 16 + lr;
            float bv = b0[col];
            #pragma unroll
            for (int mi = 0; mi < 2; ++mi)
                #pragma unroll
                for (int j = 0; j < 4; ++j) {
                    int r = wr * 32 + mi * 16 + lg * 4 + j;
                    X1s[r * X1STR + col] = f2bf(fmaxf(acc[mi][ni][j] + bv, 0.f));
                }
        }
    }
    __syncthreads();   // X1s visible; vmcnt clean

    // ---- phase 1: X2 = relu(X1 @ W1^T + b1): 64x256, K=512, counted 3-buf ----
    {
        stage256(B0, W1t, 512, 0);
        stage256(B1, W1t, 512, 32);
        short *bA = B0, *bB = B1, *bC = B2;
        f32x4 acc[2][4] = {};
        for (int k = 0; k < 15; ++k) {
            WAIT_VMCNT(2);                       // own stage(k) landed
            __builtin_amdgcn_s_barrier();        // -> collectively landed
            __builtin_amdgcn_sched_barrier(0);
            if (k + 2 < 16) stage256(bC, W1t, 512, (k + 2) * 32);
            int k0 = k * 32;
            bf16x8 a0 = *(const bf16x8*)&X1s[(wr * 32 + lr) * X1STR + k0 + lg * 8];
            bf16x8 a1 = *(const bf16x8*)&X1s[(wr * 32 + 16 + lr) * X1STR + k0 + lg * 8];
            #pragma unroll
            for (int ni = 0; ni < 4; ++ni) {
                int n = wc * 64 + ni * 16 + lr;
                bf16x8 b = *(const bf16x8*)&bA[n * 32 + swz];
                acc[0][ni] = __builtin_amdgcn_mfma_f32_16x16x32_bf16(a0, b, acc[0][ni], 0, 0, 0);
                acc[1][ni] = __builtin_amdgcn_mfma_f32_16x16x32_bf16(a1, b, acc[1][ni], 0, 0, 0);
            }
            short* t = bA; bA = bB; bB = bC; bC = t;
        }
        WAIT_VMCNT(0);
        __builtin_amdgcn_s_barrier();
        __builtin_amdgcn_sched_barrier(0);
        {   // k = 15
            int k0 = 480;
            bf16x8 a0 = *(const bf16x8*)&X1s[(wr * 32 + lr) * X1STR + k0 + lg * 8];
            bf16x8 a1 = *(const bf16x8*)&X1s[(wr * 32 + 16 + lr) * X1STR + k0 + lg * 8];
            #pragma unroll
            for (int ni = 0; ni < 4; ++ni) {
                int n = wc * 64 + ni * 16 + lr;
                bf16x8 b = *(const bf16x8*)&bA[n * 32 + swz];
                acc[0][ni] = __builtin_amdgcn_mfma_f32_16x16x32_bf16(a0, b, acc[0][ni], 0, 0, 0);
                acc[1][ni] = __builtin_amdgcn_mfma_f32_16x16x32_bf16(a1, b, acc[1][ni], 0, 0, 0);
            }
        }
        #pragma unroll
        for (int ni = 0; ni < 4; ++ni) {
            int col = wc * 64 + ni * 16 + lr;
            float bv = b1[col];
            #pragma unroll
            for (int mi = 0; mi < 2; ++mi)
                #pragma unroll
                for (int j = 0; j < 4; ++j) {
                    int r = wr * 32 + mi * 16 + lg * 4 + j;
                    X2s[r * X2STR + col] = f2bf(fmaxf(acc[mi][ni][j] + bv, 0.f));
                }
        }
    }
    __syncthreads();   // X1s dead -> As region usable; X2s visible

    // ---- gram: zero As pad cols, then wave w -> samples w*8..w*8+7 ----
    for (int x = tid; x < SPB * 27; x += 512) {
        int r = x / 27, c = x - r * 27;
        As[r * ASTR + KREAL + c] = 0;
    }
    {
        int row = lane & 31, half = lane >> 5;
        int srow = (row < NSPARSE) ? row : 0;   // lanes>=26 dup row 0; garbage
        int idxv[8];                            // lands in r,c>=26 only
        #pragma unroll
        for (int li = 0; li < 8; ++li)
            idxv[li] = sparse[(sbase + w * 8 + li) * NSPARSE + srow];

        f32x4 Ca[4], Cb[4], Na[4], Nb[4];
        {
            const float* rp = tables + ((long)srow * VOCAB + idxv[0]) * EMB + half * 8;
            #pragma unroll
            for (int t = 0; t < 4; ++t) {
                Ca[t] = *(const f32x4*)(rp + t * 16);
                Cb[t] = *(const f32x4*)(rp + t * 16 + 4);
            }
        }
        #pragma unroll
        for (int li = 0; li < 8; ++li) {
            if (li < 7) {
                const float* rp = tables + ((long)srow * VOCAB + idxv[li + 1]) * EMB + half * 8;
                #pragma unroll
                for (int t = 0; t < 4; ++t) {
                    Na[t] = *(const f32x4*)(rp + t * 16);
                    Nb[t] = *(const f32x4*)(rp + t * 16 + 4);
                }
            }
            f32x16 acc = {};
            #pragma unroll
            for (int t = 0; t < 4; ++t) {
                bf16x8 f;
                #pragma unroll
                for (int j = 0; j < 4; ++j) f[j] = f2bf(Ca[t][j]);
                #pragma unroll
                for (int j = 0; j < 4; ++j) f[4 + j] = f2bf(Cb[t][j]);
                acc = __builtin_amdgcn_mfma_f32_32x32x16_bf16(f, f, acc, 0, 0, 0);
            }
            int c = row;
            if (c < NSPARSE) {
                #pragma unroll
                for (int reg = 0; reg < 16; ++reg) {
                    int r = (reg & 3) + 8 * (reg >> 2) + 4 * half;
                    if (r < c) {
                        int p = r * (2 * NSPARSE - r - 1) / 2 + (c - r - 1);
                        As[(w * 8 + li) * ASTR + 64 + p] = f2bf(acc[reg]);
                    }
                }
            }
            #pragma unroll
            for (int t = 0; t < 4; ++t) { Ca[t] = Na[t]; Cb[t] = Nb[t]; }
        }
    }

    // ---- phase 2: dense_out -> As cols 0..63: 64x64, K=256, counted 3-buf ----
    {
        stage64(B0, W2t, 256, 0);
        stage64(B1, W2t, 256, 32);
        short *bA = B0, *bB = B1, *bC = B2;
        f32x4 acc[2] = {};
        for (int k = 0; k < 7; ++k) {
            WAIT_VMCNT(1);
            __builtin_amdgcn_s_barrier();
            __builtin_amdgcn_sched_barrier(0);
            if (k + 2 < 8) stage64(bC, W2t, 256, (k + 2) * 32);
            int k0 = k * 32;
            bf16x8 a0 = *(const bf16x8*)&X2s[(wr * 32 + lr) * X2STR + k0 + lg * 8];
            bf16x8 a1 = *(const bf16x8*)&X2s[(wr * 32 + 16 + lr) * X2STR + k0 + lg * 8];
            int n = wc * 16 + lr;
            bf16x8 b = *(const bf16x8*)&bA[n * 32 + swz];
            acc[0] = __builtin_amdgcn_mfma_f32_16x16x32_bf16(a0, b, acc[0], 0, 0, 0);
            acc[1] = __builtin_amdgcn_mfma_f32_16x16x32_bf16(a1, b, acc[1], 0, 0, 0);
            short* t = bA; bA = bB; bB = bC; bC = t;
        }
        WAIT_VMCNT(0);
        __builtin_amdgcn_s_barrier();
        __builtin_amdgcn_sched_barrier(0);
        {   // k = 7
            int k0 = 224;
            bf16x8 a0 = *(const bf16x8*)&X2s[(wr * 32 + lr) * X2STR + k0 + lg * 8];
            bf16x8 a1 = *(const bf16x8*)&X2s[(wr * 32 + 16 + lr) * X2STR + k0 + lg * 8];
            int n = wc * 16 + lr;
            bf16x8 b = *(const bf16x8*)&bA[n * 32 + swz];
            acc[0] = __builtin_amdgcn_mfma_f32_16x16x32_bf16(a0, b, acc[0], 0, 0, 0);
            acc[1] = __builtin_amdgcn_mfma_f32_16x16x32_bf16(a1, b, acc[1], 0, 0, 0);
        }
        int col = wc * 16 + lr;
        float bv = b2[col];
        #pragma unroll
        for (int mi = 0; mi < 2; ++mi)
            #pragma unroll
            for (int j = 0; j < 4; ++j) {
                int r = wr * 32 + mi * 16 + lg * 4 + j;
                As[r * ASTR + col] = f2bf(fmaxf(acc[mi][j] + bv, 0.f));
            }
    }
    __syncthreads();   // As complete (gram + dense + pads); vmcnt clean

    // ---- top GEMM: out(64x256) = As(64xK416) @ Wtt^T + bt, counted 3-buf ----
    {
        stage256(B0, Wtt, KTOP, 0);
        stage256(B1, Wtt, KTOP, 32);
        short *bA = B0, *bB = B1, *bC = B2;
        f32x4 acc[2][4] = {};
        for (int k = 0; k < 12; ++k) {
            WAIT_VMCNT(2);
            __builtin_amdgcn_s_barrier();
            __builtin_amdgcn_sched_barrier(0);
            if (k + 2 < 13) stage256(bC, Wtt, KTOP, (k + 2) * 32);
            int k0 = k * 32;
            bf16x8 a0 = *(const bf16x8*)&As[(wr * 32 + lr) * ASTR + k0 + lg * 8];
            bf16x8 a1 = *(const bf16x8*)&As[(wr * 32 + 16 + lr) * ASTR + k0 + lg * 8];
            #pragma unroll
            for (int ni = 0; ni < 4; ++ni) {
                int n = wc * 64 + ni * 16 + lr;
                bf16x8 b = *(const bf16x8*)&bA[n * 32 + swz];
                acc[0][ni] = __builtin_amdgcn_mfma_f32_16x16x32_bf16(a0, b, acc[0][ni], 0, 0, 0);
                acc[1][ni] = __builtin_amdgcn_mfma_f32_16x16x32_bf16(a1, b, acc[1][ni], 0, 0, 0);
            }
            short* t = bA; bA = bB; bB = bC; bC = t;
        }
        WAIT_VMCNT(0);
        __builtin_amdgcn_s_barrier();
        __builtin_amdgcn_sched_barrier(0);
        {   // k = 12
            int k0 = 384;
            bf16x8 a0 = *(const bf16x8*)&As[(wr * 32 + lr) * ASTR + k0 + lg * 8];
            bf16x8 a1 = *(const bf16x8*)&As[(wr * 32 + 16 + lr) * ASTR + k0 + lg * 8];
            #pragma unroll
            for (int ni = 0; ni < 4; ++ni) {
                int n = wc * 64 + ni * 16 + lr;
                bf16x8 b = *(const bf16x8*)&bA[n * 32 + swz];
                acc[0][ni] = __builtin_amdgcn_mfma_f32_16x16x32_bf16(a0, b, acc[0][ni], 0, 0, 0);
                acc[1][ni] = __builtin_amdgcn_mfma_f32_16x16x32_bf16(a1, b, acc[1][ni], 0, 0, 0);
            }
        }
        #pragma unroll
        for (int ni = 0; ni < 4; ++ni) {
            int col = wc * 64 + ni * 16 + lr;
            float bv = bt[col];
            #pragma unroll
            for (int mi = 0; mi < 2; ++mi)
                #pragma unroll
                for (int j = 0; j < 4; ++j) {
                    int r = wr * 32 + mi * 16 + lg * 4 + j;
                    out[(size_t)(sbase + r) * 256 + col] = acc[mi][ni][j] + bv;
                }
        }
    }
}

// -------------------------------------------------------------- launch ----
extern "C" void kernel_launch(void* const* d_in, const int* in_sizes, int n_in,
                              void* d_out, int out_size, void* d_ws, size_t ws_size,
                              hipStream_t stream)
{
    const float* dense  = (const float*)d_in[0];
    const int*   sparse = (const int*)  d_in[1];
    const float* tables = (const float*)d_in[2];
    const float* W0     = (const float*)d_in[3];
    const float* b0     = (const float*)d_in[4];
    const float* W1     = (const float*)d_in[5];
    const float* b1     = (const float*)d_in[6];
    const float* W2     = (const float*)d_in[7];
    const float* b2     = (const float*)d_in[8];
    const float* Wt     = (const float*)d_in[9];
    const float* bt     = (const float*)d_in[10];
    float* out = (float*)d_out;

    char* ws = (char*)d_ws;
    short* W0t = (short*)(ws);
    short* W1t = (short*)(ws + 32768);
    short* W2t = (short*)(ws + 294912);
    short* Wtt = (short*)(ws + 327680);

    prep_weights<<<264, 256, 0, stream>>>(W0, W1, W2, Wt, W0t, W1t, W2t, Wtt);

    fused_all<<<BATCH / SPB, 512, 0, stream>>>(sparse, tables, dense,
                                               W0t, b0, W1t, b1, W2t, b2,
                                               Wtt, bt, out);
}